// Round 7
// baseline (261.795 us; speedup 1.0000x reference)
//
#include <hip/hip_runtime.h>
#include <cmath>

#define N_PTS 32768
#define HID   256
#define KTEST 1024
#define MB    32       // points per mlp block
#define RS    264      // padded H row stride (528 B = 33*16): b128 2-way max (free)
#define SKC   256      // points per sk block
#define SKYB  (N_PTS / SKC)     // 128
#define SKGRID (4 * SKYB)       // 512 blocks total

typedef float  f32x4  __attribute__((ext_vector_type(4)));
typedef short  s16x8  __attribute__((ext_vector_type(8)));
typedef __bf16 bf16x8 __attribute__((ext_vector_type(8)));

__device__ __forceinline__ float b2f(unsigned short s) {
    return __uint_as_float(((unsigned int)s) << 16);
}
__device__ __forceinline__ unsigned short f2b_rne(float x) {
    unsigned int b = __float_as_uint(x);
    return (unsigned short)((b + 0x7FFFu + ((b >> 16) & 1u)) >> 16);
}
// exact split for W: x = hi + lo_f (exact), lo = RNE16(lo_f)
__device__ __forceinline__ void split2(float x, unsigned short& hi, unsigned short& lo) {
    unsigned int b = __float_as_uint(x);
    hi = (unsigned short)(b >> 16);
    float hf = __uint_as_float(b & 0xFFFF0000u);
    lo = f2b_rne(x - hf);
}
__device__ __forceinline__ float fast_tanh(float z) {
    float e = __expf(2.0f * z);
    return 1.0f - 2.0f / (e + 1.0f);
}

// ---------------------------------------------------------------------------
// W[k][n] fp32 -> hi/lo bf16 in MFMA B-fragment order:
//   frag(t,kc) = 64 lanes x 8 elems; lane (q=lane>>4, ln=lane&15) holds
//   W[kc*32 + q*8 + j][t*16 + ln], j=0..7.  elem offset = ((t*8+kc)*64+lane)*8
// Also zeroes the sk done-counter (stream-ordered before sk_loss).
// ---------------------------------------------------------------------------
__global__ __launch_bounds__(64) void wswz_kernel(
    const float* __restrict__ W1, const float* __restrict__ W2,
    unsigned short* __restrict__ Wh1, unsigned short* __restrict__ Wl1,
    unsigned short* __restrict__ Wh2, unsigned short* __restrict__ Wl2,
    unsigned int* __restrict__ counter)
{
    const int lane = threadIdx.x;      // 0..63
    const int t  = blockIdx.x;         // col tile 0..15
    const int kc = blockIdx.y;         // k chunk 0..7
    const float* W = blockIdx.z ? W2 : W1;
    unsigned short* Wh = blockIdx.z ? Wh2 : Wh1;
    unsigned short* Wl = blockIdx.z ? Wl2 : Wl1;
    const int q = lane >> 4, ln = lane & 15;
    const int n = t * 16 + ln;
    const int kbase = kc * 32 + q * 8;

    s16x8 hv, lv;
    #pragma unroll
    for (int j = 0; j < 8; ++j) {
        unsigned short h, l;
        split2(W[(kbase + j) * HID + n], h, l);
        hv[j] = (short)h; lv[j] = (short)l;
    }
    const int out = ((t * 8 + kc) * 64 + lane) * 8;
    *(s16x8*)(Wh + out) = hv;
    *(s16x8*)(Wl + out) = lv;

    if (lane == 0 && t == 0 && kc == 0 && blockIdx.z == 0)
        *counter = 0u;
}

// ---------------------------------------------------------------------------
// MLP fwd + u_xx (forward-mode AD). 32 points/block, 8 waves; wave owns 32
// output cols (nt=2). Register diet for 6 waves/SIMD (3 blocks/CU):
//   acc 48 AGPR + single-buffered W frags 16 + per-state A frags 8 + addr
//   ~= 84 unified regs (pool = 512/SIMD; 104 regs was the R6 4-wave binder).
// Single-buffered W is latency-safe at 6 waves: 116 MFMA cyc/iter x 6 >> L2.
// ---------------------------------------------------------------------------
__global__ __launch_bounds__(512, 6) void mlp_kernel(
    const float* __restrict__ x, const float* __restrict__ wq,
    const float* __restrict__ W0, const float* __restrict__ b0,
    const float* __restrict__ b1v, const float* __restrict__ b2v,
    const float* __restrict__ W3, const float* __restrict__ b3,
    const unsigned short* __restrict__ W1h, const unsigned short* __restrict__ W1l,
    const unsigned short* __restrict__ W2h, const unsigned short* __restrict__ W2l,
    float* __restrict__ u_arr, float* __restrict__ d_arr)
{
    __shared__ __align__(16) unsigned short Hb[3][MB][RS];   // 50688 B

    const int tid = threadIdx.x;
    const int gp0 = blockIdx.x * MB;

    // ---- layer 0 (1 -> 256): z'=W0[j], z''=0
    {
        const int m = tid & 31, jseg = tid >> 5;   // 16 segs x 16 cols
        const float xm = x[gp0 + m];
        #pragma unroll 4
        for (int jj = 0; jj < 16; ++jj) {
            int j = jseg * 16 + jj;
            float w = W0[j];
            float z = fmaf(xm, w, b0[j]);
            float y = fast_tanh(z);
            float s = 1.0f - y * y;
            float yp = s * w;
            float ypp = -2.0f * y * yp * w;
            Hb[0][m][j] = f2b_rne(y);
            Hb[1][m][j] = f2b_rne(yp);
            Hb[2][m][j] = f2b_rne(ypp);
        }
    }
    __syncthreads();

    const int lane = tid & 63, wv = tid >> 6;      // wv 0..7
    const int q = lane >> 4, ln = lane & 15;

    // per-wave fragment base: tiles (wv*2, wv*2+1); offsets nt*4096 + kc*512
    const int fragbase = (wv * 2) * 8 * 512 + lane * 8;

    // ---- hidden layers 1,2 (256 -> 256)
    for (int layer = 0; layer < 2; ++layer) {
        const unsigned short* __restrict__ WhW = (layer ? W2h : W1h) + fragbase;
        const unsigned short* __restrict__ WlW = (layer ? W2l : W1l) + fragbase;
        const float* __restrict__ bb = layer ? b2v : b1v;

        f32x4 acc[3][2][2];   // [state][mfrag][ntile] = 48 AGPR
        #pragma unroll
        for (int s = 0; s < 3; ++s)
            #pragma unroll
            for (int mf = 0; mf < 2; ++mf)
                #pragma unroll
                for (int nt = 0; nt < 2; ++nt)
                    acc[s][mf][nt] = (f32x4){0.f, 0.f, 0.f, 0.f};

        for (int kc = 0; kc < 8; ++kc) {
            // single-buffered W fragments (16 VGPR live)
            s16x8 bh[2], bl[2];
            #pragma unroll
            for (int nt = 0; nt < 2; ++nt) {
                const int off = nt * 4096 + kc * 512;
                bh[nt] = *(const s16x8*)(WhW + off);
                bl[nt] = *(const s16x8*)(WlW + off);
            }
            // s-outer: only one state's A-frags live (8 VGPR)
            #pragma unroll
            for (int s = 0; s < 3; ++s) {
                s16x8 a0 = *(const s16x8*)&Hb[s][ln][kc * 32 + q * 8];
                s16x8 a1 = *(const s16x8*)&Hb[s][16 + ln][kc * 32 + q * 8];
                #pragma unroll
                for (int nt = 0; nt < 2; ++nt) {
                    acc[s][0][nt] = __builtin_amdgcn_mfma_f32_16x16x32_bf16(
                        __builtin_bit_cast(bf16x8, a0),
                        __builtin_bit_cast(bf16x8, bh[nt]), acc[s][0][nt], 0, 0, 0);
                    acc[s][0][nt] = __builtin_amdgcn_mfma_f32_16x16x32_bf16(
                        __builtin_bit_cast(bf16x8, a0),
                        __builtin_bit_cast(bf16x8, bl[nt]), acc[s][0][nt], 0, 0, 0);
                    acc[s][1][nt] = __builtin_amdgcn_mfma_f32_16x16x32_bf16(
                        __builtin_bit_cast(bf16x8, a1),
                        __builtin_bit_cast(bf16x8, bh[nt]), acc[s][1][nt], 0, 0, 0);
                    acc[s][1][nt] = __builtin_amdgcn_mfma_f32_16x16x32_bf16(
                        __builtin_bit_cast(bf16x8, a1),
                        __builtin_bit_cast(bf16x8, bl[nt]), acc[s][1][nt], 0, 0, 0);
                }
            }
        }
        __syncthreads();   // all reads of old H done

        #pragma unroll
        for (int nt = 0; nt < 2; ++nt) {
            const int c = wv * 32 + nt * 16 + ln;
            const float bias = bb[c];
            #pragma unroll
            for (int mf = 0; mf < 2; ++mf) {
                #pragma unroll
                for (int i = 0; i < 4; ++i) {
                    const int r = mf * 16 + q * 4 + i;
                    float z   = acc[0][mf][nt][i] + bias;
                    float zp  = acc[1][mf][nt][i];
                    float zpp = acc[2][mf][nt][i];
                    float y  = fast_tanh(z);
                    float s  = 1.0f - y * y;
                    float yp = s * zp;
                    float ypp = fmaf(s, zpp, -2.0f * y * yp * zp);
                    Hb[0][r][c] = f2b_rne(y);
                    if (layer == 0) Hb[1][r][c] = f2b_rne(yp);  // last layer's h' never read
                    Hb[2][r][c] = f2b_rne(ypp);
                }
            }
        }
        __syncthreads();
    }

    // ---- final layer (256 -> 1); psum aliases Hb[1] (dead here)
    float* psum = (float*)&Hb[1][0][0];   // [2][16][32] floats = 4 KB
    {
        const int m = tid & 31, seg = tid >> 5;
        float su = 0.f, sx = 0.f;
        #pragma unroll 4
        for (int jj = 0; jj < 16; ++jj) {
            int j = seg * 16 + jj;
            float w3 = W3[j];
            su = fmaf(b2f(Hb[0][m][j]), w3, su);
            sx = fmaf(b2f(Hb[2][m][j]), w3, sx);
        }
        psum[(0 * 16 + seg) * 32 + m] = su;
        psum[(1 * 16 + seg) * 32 + m] = sx;
    }
    __syncthreads();
    if (tid < MB) {
        float u = b3[0], uxx = 0.f;
        #pragma unroll
        for (int s2 = 0; s2 < 16; ++s2) {
            u   += psum[s2 * 32 + tid];
            uxx += psum[(16 + s2) * 32 + tid];
        }
        const int gp = gp0 + tid;
        u_arr[gp] = u;
        float xv = x[gp];
        d_arr[gp] = -wq[gp] * (uxx + sinpif(xv));
    }
}

// ---------------------------------------------------------------------------
// sk + fused loss. Thread owns one k for a 256-point chunk; writes partial
// sums (no init needed). sin(pi*k*x) = v_sin(fract(fma(k, xl/2, fract(k*xh/2)))):
// k*(xh/2) exact (12b x 11b mantissa), fract exact, v_sin ~ulp.
// Last block (device-scope counter) reduces partials -> out.
// ---------------------------------------------------------------------------
__global__ __launch_bounds__(256) void sk_loss_kernel(
    const float* __restrict__ x, const float* __restrict__ d_arr,
    const float* __restrict__ u_arr, float* __restrict__ part,
    unsigned int* __restrict__ counter, float* __restrict__ out)
{
    __shared__ float xs_h[SKC], xs_l[SKC], ds[SKC];
    __shared__ float red[4];
    __shared__ int lastFlag;

    const int tid = threadIdx.x;
    const int k = blockIdx.x * 256 + tid;         // 0..1023 -> k+1
    const int i0 = blockIdx.y * SKC;

    {
        float xv = x[i0 + tid];
        float xh = __uint_as_float(__float_as_uint(xv) & 0xFFFFF000u);
        xs_h[tid] = xh * 0.5f;
        xs_l[tid] = (xv - xh) * 0.5f;
        ds[tid]   = d_arr[i0 + tid];
    }
    __syncthreads();

    const float kf = (float)(k + 1);
    float s = 0.f;
    #pragma unroll 8
    for (int i = 0; i < SKC; ++i) {
        float A = kf * xs_h[i];                           // exact
        float f = __builtin_amdgcn_fractf(A);             // exact mod 1
        float t = __builtin_amdgcn_fractf(fmaf(kf, xs_l[i], f));
        s = fmaf(__builtin_amdgcn_sinf(t), ds[i], s);     // sin(2*pi*t)
    }
    part[blockIdx.y * KTEST + k] = s;

    // ---- last-block loss reduction
    __threadfence();
    if (tid == 0)
        lastFlag = (atomicAdd(counter, 1u) == (unsigned)(SKGRID - 1));
    __syncthreads();
    if (!lastFlag) return;
    __threadfence();

    float a0 = 0.f, a1 = 0.f, a2 = 0.f, a3 = 0.f;
    const float* P = part + tid * 4;
    for (int yb = 0; yb < SKYB; ++yb) {
        f32x4 v = *(const f32x4*)(P + yb * KTEST);
        a0 += v[0]; a1 += v[1]; a2 += v[2]; a3 += v[3];
    }
    float sq = a0 * a0 + a1 * a1 + a2 * a2 + a3 * a3;
    #pragma unroll
    for (int off = 32; off > 0; off >>= 1) sq += __shfl_down(sq, off, 64);
    if ((tid & 63) == 0) red[tid >> 6] = sq;
    __syncthreads();
    if (tid == 0) {
        float t = red[0] + red[1] + red[2] + red[3];
        out[0] = t * (1.0f / (float)KTEST);
        float u0 = u_arr[0], uN = u_arr[N_PTS - 1];
        out[1] = 5.0f * (u0 * u0 + uN * uN);
    }
}

extern "C" void kernel_launch(void* const* d_in, const int* in_sizes, int n_in,
                              void* d_out, int out_size, void* d_ws, size_t ws_size,
                              hipStream_t stream)
{
    const float* x  = (const float*)d_in[0];
    const float* wq = (const float*)d_in[1];
    const float* W0 = (const float*)d_in[2];
    const float* b0 = (const float*)d_in[3];
    const float* W1 = (const float*)d_in[4];
    const float* b1 = (const float*)d_in[5];
    const float* W2 = (const float*)d_in[6];
    const float* b2 = (const float*)d_in[7];
    const float* W3 = (const float*)d_in[8];
    const float* b3 = (const float*)d_in[9];
    float* out = (float*)d_out;

    float* ws    = (float*)d_ws;
    float* u_arr = ws;                       // 32768 f
    float* d_arr = ws + N_PTS;               // 32768 f
    float* part  = ws + 2 * N_PTS;           // 128*1024 f
    unsigned short* W1h = (unsigned short*)(ws + 2 * N_PTS + SKYB * KTEST);
    unsigned short* W1l = W1h + HID * HID;
    unsigned short* W2h = W1l + HID * HID;
    unsigned short* W2l = W2h + HID * HID;
    unsigned int* counter = (unsigned int*)(W2l + HID * HID);

    wswz_kernel<<<dim3(16, 8, 2), 64, 0, stream>>>(W1, W2, W1h, W1l, W2h, W2l, counter);
    mlp_kernel<<<N_PTS / MB, 512, 0, stream>>>(x, wq, W0, b0, b1, b2, W3, b3,
                                               W1h, W1l, W2h, W2l, u_arr, d_arr);
    sk_loss_kernel<<<dim3(4, SKYB), 256, 0, stream>>>(x, d_arr, u_arr, part, counter, out);
}

// Round 8
// 161.834 us; speedup vs baseline: 1.6177x; 1.6177x over previous
//
#include <hip/hip_runtime.h>
#include <cmath>

#define N_PTS 32768
#define HID   256
#define KTEST 1024
#define MB    32       // points per mlp block
#define RS    264      // padded H row stride (528 B = 33*16): b128 2-way max (free)
#define SKC   256      // points per sk block
#define SKYB  (N_PTS / SKC)     // 128
#define SKGRID (4 * SKYB)       // 512 blocks total

typedef float  f32x4  __attribute__((ext_vector_type(4)));
typedef short  s16x8  __attribute__((ext_vector_type(8)));
typedef __bf16 bf16x8 __attribute__((ext_vector_type(8)));

__device__ __forceinline__ float b2f(unsigned short s) {
    return __uint_as_float(((unsigned int)s) << 16);
}
// native RNE fp32->bf16 (v_cvt_pk_bf16_f32 on gfx950); bit-identical to
// manual round-to-nearest-even, 1 instr instead of 3.
__device__ __forceinline__ unsigned short cvt16(float x) {
    return __builtin_bit_cast(unsigned short, (__bf16)x);
}
// exact split for W: x = hi + lo_f (exact), lo = RNE16(lo_f)
__device__ __forceinline__ void split2(float x, unsigned short& hi, unsigned short& lo) {
    unsigned int b = __float_as_uint(x);
    hi = (unsigned short)(b >> 16);
    float hf = __uint_as_float(b & 0xFFFF0000u);
    lo = cvt16(x - hf);
}
__device__ __forceinline__ float fast_tanh(float z) {
    float e = __expf(2.0f * z);
    return 1.0f - 2.0f / (e + 1.0f);
}

// ---------------------------------------------------------------------------
// W[k][n] fp32 -> hi/lo bf16 in MFMA B-fragment order:
//   frag(t,kc) = 64 lanes x 8 elems; lane (q=lane>>4, ln=lane&15) holds
//   W[kc*32 + q*8 + j][t*16 + ln], j=0..7.  elem offset = ((t*8+kc)*64+lane)*8
// Also zeroes the sk done-counter (stream-ordered before sk_loss).
// ---------------------------------------------------------------------------
__global__ __launch_bounds__(64) void wswz_kernel(
    const float* __restrict__ W1, const float* __restrict__ W2,
    unsigned short* __restrict__ Wh1, unsigned short* __restrict__ Wl1,
    unsigned short* __restrict__ Wh2, unsigned short* __restrict__ Wl2,
    unsigned int* __restrict__ counter)
{
    const int lane = threadIdx.x;      // 0..63
    const int t  = blockIdx.x;         // col tile 0..15
    const int kc = blockIdx.y;         // k chunk 0..7
    const float* W = blockIdx.z ? W2 : W1;
    unsigned short* Wh = blockIdx.z ? Wh2 : Wh1;
    unsigned short* Wl = blockIdx.z ? Wl2 : Wl1;
    const int q = lane >> 4, ln = lane & 15;
    const int n = t * 16 + ln;
    const int kbase = kc * 32 + q * 8;

    s16x8 hv, lv;
    #pragma unroll
    for (int j = 0; j < 8; ++j) {
        unsigned short h, l;
        split2(W[(kbase + j) * HID + n], h, l);
        hv[j] = (short)h; lv[j] = (short)l;
    }
    const int out = ((t * 8 + kc) * 64 + lane) * 8;
    *(s16x8*)(Wh + out) = hv;
    *(s16x8*)(Wl + out) = lv;

    if (lane == 0 && t == 0 && kc == 0 && blockIdx.z == 0)
        *counter = 0u;
}

// ---------------------------------------------------------------------------
// MLP fwd + u_xx (forward-mode AD). 32 points/block, 8 waves; wave owns 32
// output cols (nt=2). A (states) single RNE-bf16 in LDS; B (W) hi/lo from
// global in fragment order, double-buffered. 24 MFMA/k-iter/wave.
// REGISTER NOTE (R7 post-mortem): 104 unified regs (56 V + 48 A) is the
// structural minimum for this tile -> 4 waves/SIMD. __launch_bounds__(512,6)
// spills the accumulators to scratch (800 MB HBM traffic, 3x slower). Keep 4.
// ---------------------------------------------------------------------------
__global__ __launch_bounds__(512, 4) void mlp_kernel(
    const float* __restrict__ x, const float* __restrict__ wq,
    const float* __restrict__ W0, const float* __restrict__ b0,
    const float* __restrict__ b1v, const float* __restrict__ b2v,
    const float* __restrict__ W3, const float* __restrict__ b3,
    const unsigned short* __restrict__ W1h, const unsigned short* __restrict__ W1l,
    const unsigned short* __restrict__ W2h, const unsigned short* __restrict__ W2l,
    float* __restrict__ u_arr, float* __restrict__ d_arr)
{
    __shared__ __align__(16) unsigned short Hb[3][MB][RS];   // 50688 B

    const int tid = threadIdx.x;
    const int gp0 = blockIdx.x * MB;

    // ---- layer 0 (1 -> 256): z'=W0[j], z''=0
    {
        const int m = tid & 31, jseg = tid >> 5;   // 16 segs x 16 cols
        const float xm = x[gp0 + m];
        #pragma unroll 4
        for (int jj = 0; jj < 16; ++jj) {
            int j = jseg * 16 + jj;
            float w = W0[j];
            float z = fmaf(xm, w, b0[j]);
            float y = fast_tanh(z);
            float s = 1.0f - y * y;
            float yp = s * w;
            float ypp = -2.0f * y * yp * w;
            Hb[0][m][j] = cvt16(y);
            Hb[1][m][j] = cvt16(yp);
            Hb[2][m][j] = cvt16(ypp);
        }
    }
    __syncthreads();

    const int lane = tid & 63, wv = tid >> 6;      // wv 0..7
    const int q = lane >> 4, ln = lane & 15;

    // per-wave fragment base: tiles (wv*2, wv*2+1); offsets nt*4096 + kc*512
    const int fragbase = (wv * 2) * 8 * 512 + lane * 8;

    // ---- hidden layers 1,2 (256 -> 256)
    for (int layer = 0; layer < 2; ++layer) {
        const unsigned short* __restrict__ WhW = (layer ? W2h : W1h) + fragbase;
        const unsigned short* __restrict__ WlW = (layer ? W2l : W1l) + fragbase;
        const float* __restrict__ bb = layer ? b2v : b1v;

        f32x4 acc[3][2][2];   // [state][mfrag][ntile] = 48 AGPR
        #pragma unroll
        for (int s = 0; s < 3; ++s)
            #pragma unroll
            for (int mf = 0; mf < 2; ++mf)
                #pragma unroll
                for (int nt = 0; nt < 2; ++nt)
                    acc[s][mf][nt] = (f32x4){0.f, 0.f, 0.f, 0.f};

        s16x8 bh[2][2], bl[2][2];
        #pragma unroll
        for (int nt = 0; nt < 2; ++nt) {
            bh[0][nt] = *(const s16x8*)(WhW + nt * 4096);
            bl[0][nt] = *(const s16x8*)(WlW + nt * 4096);
        }

        int cur = 0;
        for (int kc = 0; kc < 8; ++kc) {
            const int nxt = cur ^ 1;
            if (kc < 7) {
                #pragma unroll
                for (int nt = 0; nt < 2; ++nt) {
                    const int off = nt * 4096 + (kc + 1) * 512;
                    bh[nxt][nt] = *(const s16x8*)(WhW + off);
                    bl[nxt][nt] = *(const s16x8*)(WlW + off);
                }
            }
            s16x8 av[3][2];
            #pragma unroll
            for (int s = 0; s < 3; ++s)
                #pragma unroll
                for (int mf = 0; mf < 2; ++mf)
                    av[s][mf] = *(const s16x8*)&Hb[s][mf * 16 + ln][kc * 32 + q * 8];
            #pragma unroll
            for (int s = 0; s < 3; ++s)
                #pragma unroll
                for (int mf = 0; mf < 2; ++mf)
                    #pragma unroll
                    for (int nt = 0; nt < 2; ++nt) {
                        acc[s][mf][nt] = __builtin_amdgcn_mfma_f32_16x16x32_bf16(
                            __builtin_bit_cast(bf16x8, av[s][mf]),
                            __builtin_bit_cast(bf16x8, bh[cur][nt]), acc[s][mf][nt], 0, 0, 0);
                        acc[s][mf][nt] = __builtin_amdgcn_mfma_f32_16x16x32_bf16(
                            __builtin_bit_cast(bf16x8, av[s][mf]),
                            __builtin_bit_cast(bf16x8, bl[cur][nt]), acc[s][mf][nt], 0, 0, 0);
                    }
            cur = nxt;
        }
        __syncthreads();   // all reads of old H done

        #pragma unroll
        for (int nt = 0; nt < 2; ++nt) {
            const int c = wv * 32 + nt * 16 + ln;
            const float bias = bb[c];
            #pragma unroll
            for (int mf = 0; mf < 2; ++mf) {
                #pragma unroll
                for (int i = 0; i < 4; ++i) {
                    const int r = mf * 16 + q * 4 + i;
                    float z   = acc[0][mf][nt][i] + bias;
                    float zp  = acc[1][mf][nt][i];
                    float zpp = acc[2][mf][nt][i];
                    float y  = fast_tanh(z);
                    float s  = 1.0f - y * y;
                    float yp = s * zp;
                    float ypp = fmaf(s, zpp, -2.0f * y * yp * zp);
                    Hb[0][r][c] = cvt16(y);
                    if (layer == 0) Hb[1][r][c] = cvt16(yp);  // last layer's h' never read
                    Hb[2][r][c] = cvt16(ypp);
                }
            }
        }
        __syncthreads();
    }

    // ---- final layer (256 -> 1); psum aliases Hb[1] (dead here)
    float* psum = (float*)&Hb[1][0][0];   // [2][16][32] floats = 4 KB
    {
        const int m = tid & 31, seg = tid >> 5;
        float su = 0.f, sx = 0.f;
        #pragma unroll 4
        for (int jj = 0; jj < 16; ++jj) {
            int j = seg * 16 + jj;
            float w3 = W3[j];
            su = fmaf(b2f(Hb[0][m][j]), w3, su);
            sx = fmaf(b2f(Hb[2][m][j]), w3, sx);
        }
        psum[(0 * 16 + seg) * 32 + m] = su;
        psum[(1 * 16 + seg) * 32 + m] = sx;
    }
    __syncthreads();
    if (tid < MB) {
        float u = b3[0], uxx = 0.f;
        #pragma unroll
        for (int s2 = 0; s2 < 16; ++s2) {
            u   += psum[s2 * 32 + tid];
            uxx += psum[(16 + s2) * 32 + tid];
        }
        const int gp = gp0 + tid;
        u_arr[gp] = u;
        float xv = x[gp];
        d_arr[gp] = -wq[gp] * (uxx + sinpif(xv));
    }
}

// ---------------------------------------------------------------------------
// sk + fused loss. Thread owns one k for a 256-point chunk; writes partial
// sums (no init needed). sin(pi*k*x) = v_sin(fract(fma(k, xl/2, fract(k*xh/2)))):
// k*(xh/2) exact (12b x 11b mantissa), fract exact, v_sin ~ulp.
// Last block (device-scope counter) reduces partials -> out.
// ---------------------------------------------------------------------------
__global__ __launch_bounds__(256) void sk_loss_kernel(
    const float* __restrict__ x, const float* __restrict__ d_arr,
    const float* __restrict__ u_arr, float* __restrict__ part,
    unsigned int* __restrict__ counter, float* __restrict__ out)
{
    __shared__ float xs_h[SKC], xs_l[SKC], ds[SKC];
    __shared__ float red[4];
    __shared__ int lastFlag;

    const int tid = threadIdx.x;
    const int k = blockIdx.x * 256 + tid;         // 0..1023 -> k+1
    const int i0 = blockIdx.y * SKC;

    {
        float xv = x[i0 + tid];
        float xh = __uint_as_float(__float_as_uint(xv) & 0xFFFFF000u);
        xs_h[tid] = xh * 0.5f;
        xs_l[tid] = (xv - xh) * 0.5f;
        ds[tid]   = d_arr[i0 + tid];
    }
    __syncthreads();

    const float kf = (float)(k + 1);
    float s = 0.f;
    #pragma unroll 8
    for (int i = 0; i < SKC; ++i) {
        float A = kf * xs_h[i];                           // exact
        float f = __builtin_amdgcn_fractf(A);             // exact mod 1
        float t = __builtin_amdgcn_fractf(fmaf(kf, xs_l[i], f));
        s = fmaf(__builtin_amdgcn_sinf(t), ds[i], s);     // sin(2*pi*t)
    }
    part[blockIdx.y * KTEST + k] = s;

    // ---- last-block loss reduction
    __threadfence();
    if (tid == 0)
        lastFlag = (atomicAdd(counter, 1u) == (unsigned)(SKGRID - 1));
    __syncthreads();
    if (!lastFlag) return;
    __threadfence();

    float a0 = 0.f, a1 = 0.f, a2 = 0.f, a3 = 0.f;
    const float* P = part + tid * 4;
    for (int yb = 0; yb < SKYB; ++yb) {
        f32x4 v = *(const f32x4*)(P + yb * KTEST);
        a0 += v[0]; a1 += v[1]; a2 += v[2]; a3 += v[3];
    }
    float sq = a0 * a0 + a1 * a1 + a2 * a2 + a3 * a3;
    #pragma unroll
    for (int off = 32; off > 0; off >>= 1) sq += __shfl_down(sq, off, 64);
    if ((tid & 63) == 0) red[tid >> 6] = sq;
    __syncthreads();
    if (tid == 0) {
        float t = red[0] + red[1] + red[2] + red[3];
        out[0] = t * (1.0f / (float)KTEST);
        float u0 = u_arr[0], uN = u_arr[N_PTS - 1];
        out[1] = 5.0f * (u0 * u0 + uN * uN);
    }
}

extern "C" void kernel_launch(void* const* d_in, const int* in_sizes, int n_in,
                              void* d_out, int out_size, void* d_ws, size_t ws_size,
                              hipStream_t stream)
{
    const float* x  = (const float*)d_in[0];
    const float* wq = (const float*)d_in[1];
    const float* W0 = (const float*)d_in[2];
    const float* b0 = (const float*)d_in[3];
    const float* W1 = (const float*)d_in[4];
    const float* b1 = (const float*)d_in[5];
    const float* W2 = (const float*)d_in[6];
    const float* b2 = (const float*)d_in[7];
    const float* W3 = (const float*)d_in[8];
    const float* b3 = (const float*)d_in[9];
    float* out = (float*)d_out;

    float* ws    = (float*)d_ws;
    float* u_arr = ws;                       // 32768 f
    float* d_arr = ws + N_PTS;               // 32768 f
    float* part  = ws + 2 * N_PTS;           // 128*1024 f
    unsigned short* W1h = (unsigned short*)(ws + 2 * N_PTS + SKYB * KTEST);
    unsigned short* W1l = W1h + HID * HID;
    unsigned short* W2h = W1l + HID * HID;
    unsigned short* W2l = W2h + HID * HID;
    unsigned int* counter = (unsigned int*)(W2l + HID * HID);

    wswz_kernel<<<dim3(16, 8, 2), 64, 0, stream>>>(W1, W2, W1h, W1l, W2h, W2l, counter);
    mlp_kernel<<<N_PTS / MB, 512, 0, stream>>>(x, wq, W0, b0, b1, b2, W3, b3,
                                               W1h, W1l, W2h, W2l, u_arr, d_arr);
    sk_loss_kernel<<<dim3(4, SKYB), 256, 0, stream>>>(x, d_arr, u_arr, part, counter, out);
}